// Round 1
// 473.898 us; speedup vs baseline: 1.0196x; 1.0196x over previous
//
#include <hip/hip_runtime.h>
#include <cstdint>
#include <cstddef>

// Problem constants: x[8192,4096]f32, Wp[4096,2048]i32(1 byte each),
// scales[4096,32]f32, group=128, out[8192,4096]f32.
#define TOKENS 8192
#define IN_F   4096
#define OUT_F  4096

typedef __bf16 bf16;
typedef bf16  bf16x8 __attribute__((ext_vector_type(8)));
typedef float f32x4  __attribute__((ext_vector_type(4)));

// ---------------- merged pre-pass: x f32->bf16 AND int4 W -> bf16 ----------------
__global__ void prep_kernel(const float* __restrict__ xin, bf16* __restrict__ xout,
                            const int* __restrict__ wp, const float* __restrict__ sc,
                            bf16* __restrict__ wout) {
    if (blockIdx.x < 16384) {
        size_t i = ((size_t)blockIdx.x * 256 + threadIdx.x) * 8;
        const float4* p = (const float4*)(xin + i);
        float4 a = p[0], b = p[1];
        bf16x8 r;
        r[0] = (bf16)a.x; r[1] = (bf16)a.y; r[2] = (bf16)a.z; r[3] = (bf16)a.w;
        r[4] = (bf16)b.x; r[5] = (bf16)b.y; r[6] = (bf16)b.z; r[7] = (bf16)b.w;
        *(bf16x8*)(xout + i) = r;
    } else {
        int t  = (blockIdx.x - 16384) * 256 + threadIdx.x;
        int j0 = t << 2;
        int n  = j0 >> 11;
        int g  = (j0 & 2047) >> 6;
        float s = sc[(n << 5) + g];
        int4 p = *(const int4*)(wp + j0);
        bf16x8 r;
        r[0] = (bf16)((float)((p.x & 15) - 8) * s);
        r[1] = (bf16)((float)(((p.x >> 4) & 15) - 8) * s);
        r[2] = (bf16)((float)((p.y & 15) - 8) * s);
        r[3] = (bf16)((float)(((p.y >> 4) & 15) - 8) * s);
        r[4] = (bf16)((float)((p.z & 15) - 8) * s);
        r[5] = (bf16)((float)(((p.z >> 4) & 15) - 8) * s);
        r[6] = (bf16)((float)((p.w & 15) - 8) * s);
        r[7] = (bf16)((float)(((p.w >> 4) & 15) - 8) * s);
        *(bf16x8*)(wout + ((size_t)j0 << 1)) = r;
    }
}

// ---------------- main GEMM: 256x256 tile, BK=64, 8-phase counted-vmcnt ----------------
// 512 threads = 8 waves (2M x 4N); per-wave 128x64 output = 8x4 tiles of 16x16x32 MFMA.
// LDS 128 KiB: [buf0: A 32K | B 32K][buf1: A 32K | B 32K], XOR chunk swizzle
// (LDS slot (row,s) holds global 16B-chunk (row, s^(row&7)); swizzle applied on the
// GLOBAL source side so global_load_lds dests stay linear: uniform base + lane*16).
//
// Per K-tile: 4 phases, each = {ds_reads | stage 1 half-tile | s_barrier | 16 MFMA
// (one C-quadrant x K=64, setprio-wrapped) | s_barrier}. Counted s_waitcnt vmcnt(6)
// ONCE per K-tile (3 half-tiles stay in flight across barriers).
//
// Staging half-tiles are defined to match read-death so every same-buffer staging is
// issued >=1 barrier AFTER its region's last ds_read drains (no latency assumptions):
//   A-death0 = rows {0-63,128-191}   (read only at phase 0, qr=0)  staged at phase 1
//   B-death0 = rows bit5==0          (all B read at phase 0; reg-cached) staged phase 2
//   B-death1 = rows bit5==1          staged at phase 3
//   A-death1 = rows {64-127,192-255} (read only at phase 2, qr=1)  staged next tile ph0
// Pipeline: phase p stages half-tile p+7; vmcnt(6) at each tile boundary guarantees the
// next tile is fully landed with exactly the 3 newest (dead-region) half-tiles in flight.

#define GLL(src, dst) __builtin_amdgcn_global_load_lds( \
    (const __attribute__((address_space(1))) void*)(src), \
    (__attribute__((address_space(3))) void*)(dst), 16, 0, 0)
#define BAR() asm volatile("s_barrier" ::: "memory")

__global__ __launch_bounds__(512, 2)
void gemm_kernel(const bf16* __restrict__ A, const bf16* __restrict__ B,
                 float* __restrict__ C) {
    __shared__ char smem[131072] __attribute__((aligned(128)));

    const int tid  = threadIdx.x;
    const int lane = tid & 63;
    const int w    = tid >> 6;
    const int wr   = w >> 2, wc = w & 3;
    const int lrow = lane >> 3;             // row within the wave's 8-row stage block
    const int gsw  = (lane & 7) ^ lrow;     // pre-swizzled global chunk within 128B row

    // bijective XCD swizzle (512 % 8 == 0)
    const int wg = ((blockIdx.x & 7) << 6) | (blockIdx.x >> 3);
    const int mt = wg >> 4;                 // 32 M-tiles
    const int nt = wg & 15;                 // 16 N-tiles

    const char* Abase = (const char*)A + (size_t)(mt * 256) * (IN_F * 2);
    const char* Bbase = (const char*)B + (size_t)(nt * 256) * (IN_F * 2);

    // staging global sources (per-lane, pre-swizzled)
    const char* gA[4];
#pragma unroll
    for (int t = 0; t < 4; ++t)
        gA[t] = Abase + (size_t)(t * 64 + w * 8 + lrow) * (IN_F * 2) + gsw * 16;
    const int rb = (w >> 2) * 64 + (w & 3) * 8;
    const int brow0 = rb, brow1 = rb + 128, brow2 = rb + 32, brow3 = rb + 160;
    const char* gB[4];
    gB[0] = Bbase + (size_t)(brow0 + lrow) * (IN_F * 2) + gsw * 16;
    gB[1] = Bbase + (size_t)(brow1 + lrow) * (IN_F * 2) + gsw * 16;
    gB[2] = Bbase + (size_t)(brow2 + lrow) * (IN_F * 2) + gsw * 16;
    gB[3] = Bbase + (size_t)(brow3 + lrow) * (IN_F * 2) + gsw * 16;

    char* const sm = smem;
    // wave-uniform LDS dest bases (HW adds lane*16)
#define ST_A0(b, kt) { GLL(gA[0] + (kt) * 128, sm + (b) * 65536 +     0 + w * 1024); \
                       GLL(gA[2] + (kt) * 128, sm + (b) * 65536 + 16384 + w * 1024); }
#define ST_A1(b, kt) { GLL(gA[1] + (kt) * 128, sm + (b) * 65536 +  8192 + w * 1024); \
                       GLL(gA[3] + (kt) * 128, sm + (b) * 65536 + 24576 + w * 1024); }
#define ST_B0(b, kt) { GLL(gB[0] + (kt) * 128, sm + (b) * 65536 + 32768 + brow0 * 128); \
                       GLL(gB[1] + (kt) * 128, sm + (b) * 65536 + 32768 + brow1 * 128); }
#define ST_B1(b, kt) { GLL(gB[2] + (kt) * 128, sm + (b) * 65536 + 32768 + brow2 * 128); \
                       GLL(gB[3] + (kt) * 128, sm + (b) * 65536 + 32768 + brow3 * 128); }

    const int m_lane = lane & 15, quad = lane >> 4, sw = m_lane & 7;
    const bf16x8* pA0 = (const bf16x8*)sm;
    const bf16x8* pB0 = (const bf16x8*)(sm + 32768);
    const bf16x8* pA1 = (const bf16x8*)(sm + 65536);
    const bf16x8* pB1 = (const bf16x8*)(sm + 98304);

    f32x4 acc[8][4];
#pragma unroll
    for (int i = 0; i < 8; ++i)
#pragma unroll
        for (int j = 0; j < 4; ++j) acc[i][j] = (f32x4)0.0f;

    // prologue: tile0 (all 4 halves) -> buf0; tile1 idx0..2 -> buf1; leave 3 in flight
    ST_A0(0, 0); ST_B0(0, 0); ST_B1(0, 0); ST_A1(0, 0);
    ST_A0(1, 1); ST_B0(1, 1); ST_B1(1, 1);
    asm volatile("s_waitcnt vmcnt(6)" ::: "memory");
    BAR();

#define LDA(PA, qr) \
    { _Pragma("unroll") for (int i = 0; i < 4; ++i) { \
        _Pragma("unroll") for (int kh = 0; kh < 2; ++kh) { \
            af[i][kh] = (PA)[(wr * 128 + ((qr) * 4 + i) * 16 + m_lane) * 8 + ((kh * 4 + quad) ^ sw)]; } } }
#define LDB(PB) \
    { _Pragma("unroll") for (int j = 0; j < 4; ++j) { \
        _Pragma("unroll") for (int kh = 0; kh < 2; ++kh) { \
            bfr[j][kh] = (PB)[(wc * 64 + j * 16 + m_lane) * 8 + ((kh * 4 + quad) ^ sw)]; } } }
#define MM(qr, qc) \
    { __builtin_amdgcn_s_setprio(1); \
      _Pragma("unroll") for (int i = 0; i < 4; ++i) { \
        _Pragma("unroll") for (int j = 0; j < 2; ++j) { \
          _Pragma("unroll") for (int kh = 0; kh < 2; ++kh) { \
            acc[(qr) * 4 + i][(qc) * 2 + j] = __builtin_amdgcn_mfma_f32_16x16x32_bf16( \
                af[i][kh], bfr[(qc) * 2 + j][kh], acc[(qr) * 4 + i][(qc) * 2 + j], 0, 0, 0); } } } \
      __builtin_amdgcn_s_setprio(0); }

    for (int it = 0; it < 32; ++it) {
        const int kt0 = 2 * it;
        const int kt1 = kt0 + 1;
        const bool more = (it < 31);
        {   // ---- tile kt0 from buf0 ----
            bf16x8 af[4][2], bfr[4][2];
            LDA(pA0, 0); LDB(pB0);                 // phase 0: 16 ds_read_b128
            ST_A1(1, kt1);                         //   stage tile kt0+1 idx3 -> buf1
            BAR(); MM(0, 0); BAR();
            if (more) ST_A0(0, kt0 + 2);           // phase 1 (region dead since ph0)
            BAR(); MM(0, 1); BAR();
            LDA(pA0, 1);                           // phase 2: 8 ds_read_b128
            if (more) ST_B0(0, kt0 + 2);
            BAR(); MM(1, 0); BAR();
            if (more) ST_B1(0, kt0 + 2);           // phase 3
            if (more) { asm volatile("s_waitcnt vmcnt(6)" ::: "memory"); }
            else      { asm volatile("s_waitcnt vmcnt(0)" ::: "memory"); }
            BAR(); MM(1, 1); BAR();
        }
        {   // ---- tile kt1 from buf1 ----
            bf16x8 af[4][2], bfr[4][2];
            LDA(pA1, 0); LDB(pB1);                 // phase 0
            if (more) ST_A1(0, kt1 + 1);           //   stage tile kt1+1 idx3 -> buf0
            BAR(); MM(0, 0); BAR();
            if (more) ST_A0(1, kt1 + 2);           // phase 1
            BAR(); MM(0, 1); BAR();
            LDA(pA1, 1);                           // phase 2
            if (more) ST_B0(1, kt1 + 2);
            BAR(); MM(1, 0); BAR();
            if (more) ST_B1(1, kt1 + 2);           // phase 3
            if (more) { asm volatile("s_waitcnt vmcnt(6)" ::: "memory"); }
            BAR(); MM(1, 1); BAR();
        }
    }

    // epilogue: C/D layout col=lane&15, row=quad*4+reg (m89-verified)
    const size_t crow0 = (size_t)(mt * 256 + wr * 128 + quad * 4) * OUT_F
                       + (size_t)(nt * 256 + wc * 64 + m_lane);
#pragma unroll
    for (int i = 0; i < 8; ++i)
#pragma unroll
        for (int r = 0; r < 4; ++r) {
            float* cp = C + crow0 + (size_t)(i * 16 + r) * OUT_F;
#pragma unroll
            for (int j = 0; j < 4; ++j) cp[j * 16] = acc[i][j][r];
        }
}

// ---------------- fallback (only if ws too small): slow but correct ----------------
__global__ void naive_kernel(const float* __restrict__ x, const int* __restrict__ wp,
                             const float* __restrict__ sc, float* __restrict__ out) {
    int o = blockIdx.x * 256 + threadIdx.x;
    int t = o >> 12, n = o & 4095;
    const float* xr = x + (size_t)t * IN_F;
    const int*   wr2 = wp + (size_t)n * (IN_F / 2);
    float acc = 0.f;
    for (int g = 0; g < 32; ++g) {
        float s = sc[n * 32 + g];
        float part = 0.f;
        for (int j = 0; j < 64; ++j) {
            int p = wr2[g * 64 + j];
            part += xr[g * 128 + 2 * j]     * (float)((p & 15) - 8);
            part += xr[g * 128 + 2 * j + 1] * (float)(((p >> 4) & 15) - 8);
        }
        acc += part * s;
    }
    out[o] = acc;
}

extern "C" void kernel_launch(void* const* d_in, const int* in_sizes, int n_in,
                              void* d_out, int out_size, void* d_ws, size_t ws_size,
                              hipStream_t stream) {
    const float* x  = (const float*)d_in[0];
    const int*   wp = (const int*)d_in[1];
    const float* sc = (const float*)d_in[2];
    float* out = (float*)d_out;

    const size_t xb_bytes = (size_t)TOKENS * IN_F * 2;   // 64 MiB
    const size_t wb_bytes = (size_t)OUT_F * IN_F * 2;    // 32 MiB

    if (ws_size >= xb_bytes + wb_bytes) {
        bf16* xb = (bf16*)d_ws;
        bf16* wb = (bf16*)((char*)d_ws + xb_bytes);
        prep_kernel<<<dim3(16384 + 8192), dim3(256), 0, stream>>>(x, xb, wp, sc, wb);
        gemm_kernel<<<dim3((TOKENS / 256) * (OUT_F / 256)), dim3(512), 0, stream>>>(xb, wb, out);
    } else {
        naive_kernel<<<dim3((TOKENS * OUT_F) / 256), dim3(256), 0, stream>>>(x, wp, sc, out);
    }
}

// Round 2
// 444.294 us; speedup vs baseline: 1.0875x; 1.0666x over previous
//
#include <hip/hip_runtime.h>
#include <cstdint>
#include <cstddef>

// Problem constants: x[8192,4096]f32, Wp[4096,2048]i32(1 byte each),
// scales[4096,32]f32, group=128, out[8192,4096]f32.
#define TOKENS 8192
#define IN_F   4096
#define OUT_F  4096

typedef __bf16 bf16;
typedef bf16  bf16x8 __attribute__((ext_vector_type(8)));
typedef float f32x4  __attribute__((ext_vector_type(4)));

// ---------------- merged pre-pass: x f32->bf16 AND int4 W -> bf16 ----------------
__global__ void prep_kernel(const float* __restrict__ xin, bf16* __restrict__ xout,
                            const int* __restrict__ wp, const float* __restrict__ sc,
                            bf16* __restrict__ wout) {
    if (blockIdx.x < 16384) {
        size_t i = ((size_t)blockIdx.x * 256 + threadIdx.x) * 8;
        const float4* p = (const float4*)(xin + i);
        float4 a = p[0], b = p[1];
        bf16x8 r;
        r[0] = (bf16)a.x; r[1] = (bf16)a.y; r[2] = (bf16)a.z; r[3] = (bf16)a.w;
        r[4] = (bf16)b.x; r[5] = (bf16)b.y; r[6] = (bf16)b.z; r[7] = (bf16)b.w;
        *(bf16x8*)(xout + i) = r;
    } else {
        int t  = (blockIdx.x - 16384) * 256 + threadIdx.x;
        int j0 = t << 2;
        int n  = j0 >> 11;
        int g  = (j0 & 2047) >> 6;
        float s = sc[(n << 5) + g];
        int4 p = *(const int4*)(wp + j0);
        bf16x8 r;
        r[0] = (bf16)((float)((p.x & 15) - 8) * s);
        r[1] = (bf16)((float)(((p.x >> 4) & 15) - 8) * s);
        r[2] = (bf16)((float)((p.y & 15) - 8) * s);
        r[3] = (bf16)((float)(((p.y >> 4) & 15) - 8) * s);
        r[4] = (bf16)((float)((p.z & 15) - 8) * s);
        r[5] = (bf16)((float)(((p.z >> 4) & 15) - 8) * s);
        r[6] = (bf16)((float)((p.w & 15) - 8) * s);
        r[7] = (bf16)((float)(((p.w >> 4) & 15) - 8) * s);
        *(bf16x8*)(wout + ((size_t)j0 << 1)) = r;
    }
}

// ---------------- main GEMM: 256x256 tile, BK=64, 4-phase/K-tile counted-vmcnt ----------------
// 512 threads = 8 waves (2M x 4N); per-wave 128x64 output = 8x4 tiles of 16x16x32 MFMA.
// LDS 128 KiB double buffer, XOR chunk swizzle (LDS slot (row,s) holds global chunk
// (row, s^(row&7)); swizzle applied on the GLOBAL source side, LDS dests linear).
//
// Phase p = [ds_reads(p) | 1 stage | (vmcnt at ph3) | s_barrier+sched_barrier(0) |
//            16 MFMA setprio-wrapped].  ONE barrier per phase: a wave passes BAR(p)
// only after issuing MFMA(p-1), whose lgkm wait drained its reads(p-1) -> any write
// issued after BAR(p) is WAR-safe vs reads consumed at phase p-1 or earlier.
//
// Fragment reads:  ph0: A0-frags(8) + B-qc0-frags(4); ph1: B-qc1(4); ph2: A1(8); ph3: 0.
// Region read phase:   A0:0  B0(bit5==0):0  B1(bit5==1):1  A1:2
// Stage slots (>= read-phase+2, or inactive buffer):
//   ph0: ST_B1(next tile)   [other buffer, read-drained >=2 barriers ago]
//   ph1: ST_A1(next tile)   [other buffer]
//   ph2: ST_A0(tile+2)      [this buffer, A0 read ph0, drained by BAR(ph1)]
//   ph3: ST_B0(tile+2)      [this buffer, B0 read ph0]
// vmcnt(4) once per tile at ph3: the 2 newest half-tiles (A0/B0 of tile+2) stay in
// flight; B1/A1 of tile+1 (issued ph0/ph1) are forced landed before tile+1 reads them.
// Tail: last two tiles drain with vmcnt(0) / no stage.

#define GLL(src, dst) __builtin_amdgcn_global_load_lds( \
    (const __attribute__((address_space(1))) void*)(src), \
    (__attribute__((address_space(3))) void*)(dst), 16, 0, 0)
#define BARX() { __builtin_amdgcn_s_barrier(); __builtin_amdgcn_sched_barrier(0); }

__global__ __launch_bounds__(512, 2)
void gemm_kernel(const bf16* __restrict__ A, const bf16* __restrict__ B,
                 float* __restrict__ C) {
    __shared__ char smem[131072] __attribute__((aligned(128)));

    const int tid  = threadIdx.x;
    const int lane = tid & 63;
    const int w    = tid >> 6;
    const int wr   = w >> 2, wc = w & 3;
    const int lrow = lane >> 3;             // row within the wave's 8-row stage block
    const int gsw  = (lane & 7) ^ lrow;     // pre-swizzled global chunk within 128B row

    // bijective XCD swizzle (512 % 8 == 0)
    const int wg = ((blockIdx.x & 7) << 6) | (blockIdx.x >> 3);
    const int mt = wg >> 4;                 // 32 M-tiles
    const int nt = wg & 15;                 // 16 N-tiles

    const char* Abase = (const char*)A + (size_t)(mt * 256) * (IN_F * 2);
    const char* Bbase = (const char*)B + (size_t)(nt * 256) * (IN_F * 2);

    const char* gA[4];
#pragma unroll
    for (int t = 0; t < 4; ++t)
        gA[t] = Abase + (size_t)(t * 64 + w * 8 + lrow) * (IN_F * 2) + gsw * 16;
    const int rb = (w >> 2) * 64 + (w & 3) * 8;
    const int brow0 = rb, brow1 = rb + 128, brow2 = rb + 32, brow3 = rb + 160;
    const char* gB[4];
    gB[0] = Bbase + (size_t)(brow0 + lrow) * (IN_F * 2) + gsw * 16;
    gB[1] = Bbase + (size_t)(brow1 + lrow) * (IN_F * 2) + gsw * 16;
    gB[2] = Bbase + (size_t)(brow2 + lrow) * (IN_F * 2) + gsw * 16;
    gB[3] = Bbase + (size_t)(brow3 + lrow) * (IN_F * 2) + gsw * 16;

    char* const sm = smem;
    // wave-uniform LDS dest bases (HW adds lane*16)
#define ST_A0(b, kt) { GLL(gA[0] + (kt) * 128, sm + (b) * 65536 +     0 + w * 1024); \
                       GLL(gA[2] + (kt) * 128, sm + (b) * 65536 + 16384 + w * 1024); }
#define ST_A1(b, kt) { GLL(gA[1] + (kt) * 128, sm + (b) * 65536 +  8192 + w * 1024); \
                       GLL(gA[3] + (kt) * 128, sm + (b) * 65536 + 24576 + w * 1024); }
#define ST_B0(b, kt) { GLL(gB[0] + (kt) * 128, sm + (b) * 65536 + 32768 + brow0 * 128); \
                       GLL(gB[1] + (kt) * 128, sm + (b) * 65536 + 32768 + brow1 * 128); }
#define ST_B1(b, kt) { GLL(gB[2] + (kt) * 128, sm + (b) * 65536 + 32768 + brow2 * 128); \
                       GLL(gB[3] + (kt) * 128, sm + (b) * 65536 + 32768 + brow3 * 128); }

    const int m_lane = lane & 15, quad = lane >> 4, sw = m_lane & 7;
    const bf16x8* pA0 = (const bf16x8*)sm;
    const bf16x8* pB0 = (const bf16x8*)(sm + 32768);
    const bf16x8* pA1 = (const bf16x8*)(sm + 65536);
    const bf16x8* pB1 = (const bf16x8*)(sm + 98304);

    f32x4 acc[8][4];
#pragma unroll
    for (int i = 0; i < 8; ++i)
#pragma unroll
        for (int j = 0; j < 4; ++j) acc[i][j] = (f32x4)0.0f;

    // prologue: tile0 fully; tile1's A0/B0; leave the 2 newest half-tiles in flight
    ST_A0(0, 0); ST_B0(0, 0); ST_B1(0, 0); ST_A1(0, 0);
    ST_A0(1, 1); ST_B0(1, 1);
    asm volatile("s_waitcnt vmcnt(4)" ::: "memory");
    __builtin_amdgcn_s_barrier();

#define LDA(dst, PA, qr) \
    { _Pragma("unroll") for (int i = 0; i < 4; ++i) { \
        _Pragma("unroll") for (int kh = 0; kh < 2; ++kh) { \
            dst[i][kh] = (PA)[(wr * 128 + ((qr) * 4 + i) * 16 + m_lane) * 8 + ((kh * 4 + quad) ^ sw)]; } } }
#define LDBq(PB, qc) \
    { _Pragma("unroll") for (int j = 0; j < 2; ++j) { \
        _Pragma("unroll") for (int kh = 0; kh < 2; ++kh) { \
            bfr[(qc) * 2 + j][kh] = (PB)[(wc * 64 + ((qc) * 2 + j) * 16 + m_lane) * 8 + ((kh * 4 + quad) ^ sw)]; } } }
#define MM(afv, qr, qc) \
    { __builtin_amdgcn_s_setprio(1); \
      _Pragma("unroll") for (int i = 0; i < 4; ++i) { \
        _Pragma("unroll") for (int j = 0; j < 2; ++j) { \
          _Pragma("unroll") for (int kh = 0; kh < 2; ++kh) { \
            acc[(qr) * 4 + i][(qc) * 2 + j] = __builtin_amdgcn_mfma_f32_16x16x32_bf16( \
                afv[i][kh], bfr[(qc) * 2 + j][kh], acc[(qr) * 4 + i][(qc) * 2 + j], 0, 0, 0); } } } \
      __builtin_amdgcn_s_setprio(0); }

    for (int it = 0; it < 32; ++it) {
        const int kt0 = 2 * it;
        const int kt1 = kt0 + 1;
        const bool more = (it < 31);
        {   // ---- tile kt0 from buf0 ----
            bf16x8 af0[4][2], af1[4][2], bfr[4][2];
            LDA(af0, pA0, 0); LDBq(pB0, 0);        // ph0: 12 ds_read_b128
            ST_B1(1, kt1);                         //   buf1.B1 for tile kt1
            BARX(); MM(af0, 0, 0);
            LDBq(pB0, 1);                          // ph1: 4 ds_read_b128
            ST_A1(1, kt1);                         //   buf1.A1 for tile kt1
            BARX(); MM(af0, 0, 1);
            LDA(af1, pA0, 1);                      // ph2: 8 ds_read_b128
            if (more) ST_A0(0, kt0 + 2);           //   buf0.A0 (read-drained at ph0)
            BARX(); MM(af1, 1, 0);
            if (more) {                            // ph3: no reads
                ST_B0(0, kt0 + 2);
                asm volatile("s_waitcnt vmcnt(4)" ::: "memory");
            } else {
                asm volatile("s_waitcnt vmcnt(0)" ::: "memory");
            }
            BARX(); MM(af1, 1, 1);
        }
        {   // ---- tile kt1 from buf1 ----
            bf16x8 af0[4][2], af1[4][2], bfr[4][2];
            LDA(af0, pA1, 0); LDBq(pB1, 0);        // ph0
            if (more) ST_B1(0, kt1 + 1);           //   buf0.B1 for tile kt1+1
            BARX(); MM(af0, 0, 0);
            LDBq(pB1, 1);                          // ph1
            if (more) ST_A1(0, kt1 + 1);           //   buf0.A1
            BARX(); MM(af0, 0, 1);
            LDA(af1, pA1, 1);                      // ph2
            if (more) ST_A0(1, kt1 + 2);           //   buf1.A0
            BARX(); MM(af1, 1, 0);
            if (more) {                            // ph3
                ST_B0(1, kt1 + 2);
                asm volatile("s_waitcnt vmcnt(4)" ::: "memory");
            }
            BARX(); MM(af1, 1, 1);
        }
    }

    // epilogue: C/D layout col=lane&15, row=quad*4+reg (m89-verified)
    const size_t crow0 = (size_t)(mt * 256 + wr * 128 + quad * 4) * OUT_F
                       + (size_t)(nt * 256 + wc * 64 + m_lane);
#pragma unroll
    for (int i = 0; i < 8; ++i)
#pragma unroll
        for (int r = 0; r < 4; ++r) {
            float* cp = C + crow0 + (size_t)(i * 16 + r) * OUT_F;
#pragma unroll
            for (int j = 0; j < 4; ++j) cp[j * 16] = acc[i][j][r];
        }
}

// ---------------- fallback (only if ws too small): slow but correct ----------------
__global__ void naive_kernel(const float* __restrict__ x, const int* __restrict__ wp,
                             const float* __restrict__ sc, float* __restrict__ out) {
    int o = blockIdx.x * 256 + threadIdx.x;
    int t = o >> 12, n = o & 4095;
    const float* xr = x + (size_t)t * IN_F;
    const int*   wr2 = wp + (size_t)n * (IN_F / 2);
    float acc = 0.f;
    for (int g = 0; g < 32; ++g) {
        float s = sc[n * 32 + g];
        float part = 0.f;
        for (int j = 0; j < 64; ++j) {
            int p = wr2[g * 64 + j];
            part += xr[g * 128 + 2 * j]     * (float)((p & 15) - 8);
            part += xr[g * 128 + 2 * j + 1] * (float)(((p >> 4) & 15) - 8);
        }
        acc += part * s;
    }
    out[o] = acc;
}

extern "C" void kernel_launch(void* const* d_in, const int* in_sizes, int n_in,
                              void* d_out, int out_size, void* d_ws, size_t ws_size,
                              hipStream_t stream) {
    const float* x  = (const float*)d_in[0];
    const int*   wp = (const int*)d_in[1];
    const float* sc = (const float*)d_in[2];
    float* out = (float*)d_out;

    const size_t xb_bytes = (size_t)TOKENS * IN_F * 2;   // 64 MiB
    const size_t wb_bytes = (size_t)OUT_F * IN_F * 2;    // 32 MiB

    if (ws_size >= xb_bytes + wb_bytes) {
        bf16* xb = (bf16*)d_ws;
        bf16* wb = (bf16*)((char*)d_ws + xb_bytes);
        prep_kernel<<<dim3(16384 + 8192), dim3(256), 0, stream>>>(x, xb, wp, sc, wb);
        gemm_kernel<<<dim3((TOKENS / 256) * (OUT_F / 256)), dim3(512), 0, stream>>>(xb, wb, out);
    } else {
        naive_kernel<<<dim3((TOKENS * OUT_F) / 256), dim3(256), 0, stream>>>(x, wp, sc, out);
    }
}